// Round 7
// baseline (259.446 us; speedup 1.0000x reference)
//
#include <hip/hip_runtime.h>

// KAN-PINN forward, MI355X — round 7.
// Layers 1,2: NO transcendentals. tanh via [7/6] Pade (valid: |z|<=2.7 since
// |h|<=1, |W1|<=2.2, |B1|<=0.45; Pade err ~1e-7 there) + int-magic+2NR recip,
// all in PACKED fp32 (v_pk_*_f32, 2 elems/op) pairing adjacent k.
// Weights stay wave-uniform SGPR pairs consumed directly as the one allowed
// SGPR source per VOP3P op (zero v_mov). 18 packed-slot ops / 2 elems.

typedef float v2f __attribute__((ext_vector_type(2)));

#define C2L 2.88539008177792681472f  // 2*log2(e)

__device__ __forceinline__ v2f pk_mul_vv(v2f a, v2f b) {
  v2f d; asm("v_pk_mul_f32 %0, %1, %2" : "=v"(d) : "v"(a), "v"(b)); return d;
}
__device__ __forceinline__ v2f pk_mul_vs(v2f a, v2f b) {
  v2f d; asm("v_pk_mul_f32 %0, %1, %2" : "=v"(d) : "v"(a), "s"(b)); return d;
}
__device__ __forceinline__ v2f pk_add_vs(v2f a, v2f b) {
  v2f d; asm("v_pk_add_f32 %0, %1, %2" : "=v"(d) : "v"(a), "s"(b)); return d;
}
__device__ __forceinline__ v2f pk_fma_vvs(v2f a, v2f b, v2f c) {
  v2f d; asm("v_pk_fma_f32 %0, %1, %2, %3" : "=v"(d) : "v"(a), "v"(b), "s"(c)); return d;
}
__device__ __forceinline__ v2f pk_fma_svv(v2f a, v2f b, v2f c) {
  v2f d; asm("v_pk_fma_f32 %0, %1, %2, %3" : "=v"(d) : "s"(a), "v"(b), "v"(c)); return d;
}

__device__ __forceinline__ float tanh_hw(float z) {
  float e = __builtin_amdgcn_exp2f(z * C2L);
  float r = __builtin_amdgcn_rcpf(1.0f + e);
  return fmaf(r, -2.0f, 1.0f);
}

// Returns T = sum over (i,k) of  -W2*tanh(h_i*W1+B1)  for one j-row.
// hcol = &hs[0][lane], stride 64 floats per i.
static __device__ __forceinline__ float kan_row_packed(
    const float* __restrict__ W1, const float* __restrict__ B1,
    const float* __restrict__ W2, int j, const float* hcol)
{
  const v2f* __restrict__ w1v = (const v2f*)(W1 + j * 512);
  const v2f* __restrict__ b1v = (const v2f*)(B1 + j * 512);
  const v2f* __restrict__ w2v = (const v2f*)(W2 + j * 512);

  const v2f c378    = {378.f, 378.f};
  const v2f c17325  = {17325.f, 17325.f};
  const v2f c135135 = {135135.f, 135135.f};
  const v2f c28     = {28.f, 28.f};
  const v2f c3150   = {3150.f, 3150.f};
  const v2f c62370  = {62370.f, 62370.f};
  const v2f ctwo    = {2.f, 2.f};
  const v2f cntwo   = {-2.f, -2.f};

  v2f a0 = {0.f, 0.f}, a1 = {0.f, 0.f}, a2 = {0.f, 0.f}, a3 = {0.f, 0.f};

  for (int i = 0; i < 64; ++i) {
    const float h = hcol[i * 64];
    const v2f hh = {h, h};
    const int q = i * 4;
#pragma unroll
    for (int p = 0; p < 4; ++p) {
      const v2f w1 = w1v[q + p];          // wave-uniform -> s_load pair
      const v2f b1 = b1v[q + p];
      const v2f w2 = w2v[q + p];
      v2f z  = pk_add_vs(pk_mul_vs(hh, w1), b1);
      v2f u  = pk_mul_vv(z, z);
      v2f n  = pk_add_vs(u, c378);
      n      = pk_fma_vvs(u, n, c17325);
      n      = pk_fma_vvs(u, n, c135135);
      v2f zn = pk_mul_vv(z, n);            // z * num(u)
      v2f d  = pk_fma_vvs(u, c28, c3150);
      d      = pk_fma_vvs(u, d, c62370);
      d      = pk_fma_vvs(u, d, c135135);  // den(u)
      v2f r;                               // int-magic seed (2 scalar v_sub)
      r.x = __int_as_float(0x7EF311C2 - __float_as_int(d.x));
      r.y = __int_as_float(0x7EF311C2 - __float_as_int(d.y));
      v2f m  = pk_fma_vvs(d, r, cntwo);    // d*r - 2
      r      = pk_mul_vv(r, m);            // = -r1
      v2f w  = pk_fma_vvs(d, r, ctwo);     // 2 - d*r1
      r      = pk_mul_vv(r, w);            // = -1/den (to 2.6e-6)
      v2f th = pk_mul_vv(zn, r);           // = -tanh(z)
      v2f* ap = (p == 0) ? &a0 : (p == 1) ? &a1 : (p == 2) ? &a2 : &a3;
      *ap = pk_fma_svv(w2, th, *ap);       // acc += -W2*tanh
    }
  }
  const v2f s01 = pk_mul_vv(a0, (v2f){1.f, 1.f});  // keep simple: sum below
  (void)s01;
  float T = (a0.x + a0.y) + (a1.x + a1.y) + (a2.x + a2.y) + (a3.x + a3.y);
  return T;
}

// ---------------- K0: layer0 + out init ----------------
__global__ __launch_bounds__(256) void kan_layer0(
    const float* __restrict__ x, const float* __restrict__ t,
    const float* __restrict__ W1, const float* __restrict__ B1,   // (64,2,8)
    const float* __restrict__ W2, const float* __restrict__ B2,   // (64,2,8),(64,2)
    const float* __restrict__ bout,
    float* __restrict__ hA,      // [64][8192] = tanh h0 (unscaled)
    float* __restrict__ out)     // (8192,) <- b_out
{
  const int tid  = threadIdx.x;
  const int lane = tid & 63;
  const int wave = __builtin_amdgcn_readfirstlane(tid >> 6);
  const int bx = blockIdx.x, by = blockIdx.y;

  if (by == 0 && bx < 32) out[bx * 256 + tid] = bout[0];

  const int n  = bx * 64 + lane;
  const int j0 = by * 16 + wave * 4;
  const float hx = x[n], ht = t[n];
#pragma unroll
  for (int jj = 0; jj < 4; ++jj) {
    const int j = j0 + jj;
    float a0 = B2[j * 2 + 0];
    float a1 = B2[j * 2 + 1];
#pragma unroll
    for (int k = 0; k < 8; ++k) {
      float z0 = fmaf(hx, W1[j * 16 + k], B1[j * 16 + k]);
      a0 = fmaf(W2[j * 16 + k], tanh_hw(z0), a0);
      float z1 = fmaf(ht, W1[j * 16 + 8 + k], B1[j * 16 + 8 + k]);
      a1 = fmaf(W2[j * 16 + 8 + k], tanh_hw(z1), a1);
    }
    hA[j * 8192 + n] = tanh_hw(a0 + a1);
  }
}

// ---------------- K1: layer1 (packed Pade) ----------------
__global__ __launch_bounds__(256, 8) void kan_layer1(
    const float* __restrict__ hin,   // [64][8192] tanh h0
    const float* __restrict__ W1,    // (64,64,8)
    const float* __restrict__ B1,    // (64,64,8)
    const float* __restrict__ W2,    // (64,64,8)
    const float* __restrict__ B2,    // (64,64)
    float* __restrict__ hout)        // [64][8192] tanh h1
{
  __shared__ float hs[64][64];
  const int tid  = threadIdx.x;
  const int lane = tid & 63;
  const int wave = __builtin_amdgcn_readfirstlane(tid >> 6);
  const int n    = blockIdx.x * 64 + lane;

#pragma unroll
  for (int r = 0; r < 16; ++r) {
    const int i = r * 4 + wave;
    hs[i][lane] = hin[i * 8192 + n];
  }
  __syncthreads();

  const int j = blockIdx.y * 4 + wave;

  // S = sum_i B2[j,i]
  float sp = B2[j * 64 + lane];
#pragma unroll
  for (int off = 32; off; off >>= 1) sp += __shfl_xor(sp, off);

  const float T = kan_row_packed(W1, B1, W2, j, &hs[0][lane]);
  const float y = sp - T;                    // S + sum(W2*tanh)
  hout[j * 8192 + n] = tanh_hw(y);
}

// ---------------- K2: layer2 + head (packed Pade) ----------------
__global__ __launch_bounds__(256, 8) void kan_layer2(
    const float* __restrict__ hin,   // [64][8192] tanh h1
    const float* __restrict__ W1,    // (64,64,8)
    const float* __restrict__ B1,    // (64,64,8)
    const float* __restrict__ W2,    // (64,64,8)
    const float* __restrict__ B2,    // (64,64)
    const float* __restrict__ Wout,  // (1,64)
    float* __restrict__ out)         // (8192,) += partials
{
  __shared__ float hs[64][64];
  __shared__ float red[4][64];
  const int tid  = threadIdx.x;
  const int lane = tid & 63;
  const int wave = __builtin_amdgcn_readfirstlane(tid >> 6);
  const int n    = blockIdx.x * 64 + lane;

#pragma unroll
  for (int r = 0; r < 16; ++r) {
    const int i = r * 4 + wave;
    hs[i][lane] = hin[i * 8192 + n];
  }
  __syncthreads();

  const int j = blockIdx.y * 4 + wave;

  float sp = B2[j * 64 + lane];
#pragma unroll
  for (int off = 32; off; off >>= 1) sp += __shfl_xor(sp, off);

  const float T = kan_row_packed(W1, B1, W2, j, &hs[0][lane]);
  const float y = sp - T;
  const float h2 = tanh_hw(y);

  red[wave][lane] = h2 * Wout[j];
  __syncthreads();
  if (wave == 0) {
    const float pblk = (red[0][lane] + red[1][lane]) + (red[2][lane] + red[3][lane]);
    atomicAdd(&out[n], pblk);
  }
}

extern "C" void kernel_launch(void* const* d_in, const int* in_sizes, int n_in,
                              void* d_out, int out_size, void* d_ws, size_t ws_size,
                              hipStream_t stream) {
  const float* x    = (const float*)d_in[0];
  const float* t    = (const float*)d_in[1];
  const float* W1_0 = (const float*)d_in[2];
  const float* B1_0 = (const float*)d_in[3];
  const float* W2_0 = (const float*)d_in[4];
  const float* B2_0 = (const float*)d_in[5];
  const float* W1_1 = (const float*)d_in[6];
  const float* B1_1 = (const float*)d_in[7];
  const float* W2_1 = (const float*)d_in[8];
  const float* B2_1 = (const float*)d_in[9];
  const float* W1_2 = (const float*)d_in[10];
  const float* B1_2 = (const float*)d_in[11];
  const float* W2_2 = (const float*)d_in[12];
  const float* B2_2 = (const float*)d_in[13];
  const float* Wout = (const float*)d_in[14];
  const float* bout = (const float*)d_in[15];
  float* out = (float*)d_out;

  float* hA = (float*)d_ws;            // [64][8192] = 2 MB
  float* hB = hA + 64 * 8192;          // [64][8192] = 2 MB

  kan_layer0<<<dim3(128, 4), 256, 0, stream>>>(
      x, t, W1_0, B1_0, W2_0, B2_0, bout, hA, out);
  kan_layer1<<<dim3(128, 16), 256, 0, stream>>>(hA, W1_1, B1_1, W2_1, B2_1, hB);
  kan_layer2<<<dim3(128, 16), 256, 0, stream>>>(hB, W1_2, B1_2, W2_2, B2_2, Wout, out);
}

// Round 9
// 207.099 us; speedup vs baseline: 1.2528x; 1.2528x over previous
//
#include <hip/hip_runtime.h>

// KAN-PINN forward, MI355X — round 9 (= r8 with the dropped SUM(W2) bug fixed).
// S must be sum(B2 row) + sum(W2 row): y = S - 2*sum(W2*sigmoid).
// A/B: K1 = layer1 with float4 weight loads; K2 = layer2+head scalar-load control.

#define C2L 2.88539008177792681472f  // 2*log2(e)

__device__ __forceinline__ float tanh_hw(float z) {
  float e = __builtin_amdgcn_exp2f(z * C2L);
  float r = __builtin_amdgcn_rcpf(1.0f + e);
  return fmaf(r, -2.0f, 1.0f);
}

// ---------------- K0: layer0 + prep side tasks ----------------
__global__ __launch_bounds__(256) void kan_layer0(
    const float* __restrict__ x, const float* __restrict__ t,
    const float* __restrict__ W1, const float* __restrict__ B1,   // (64,2,8)
    const float* __restrict__ W2, const float* __restrict__ B2,   // (64,2,8),(64,2)
    const float* __restrict__ B1_1, const float* __restrict__ B1_2,
    const float* __restrict__ bout,
    float* __restrict__ hA,      // [64][8192] = C2L * h0
    float* __restrict__ B1c1, float* __restrict__ B1c2,
    float* __restrict__ out)     // (8192,) <- b_out
{
  const int tid  = threadIdx.x;
  const int lane = tid & 63;
  const int wave = __builtin_amdgcn_readfirstlane(tid >> 6);
  const int bx = blockIdx.x, by = blockIdx.y;
  const int flat = by * 128 + bx;

  if (flat < 128) {
    B1c1[flat * 256 + tid] = B1_1[flat * 256 + tid] * C2L;
  } else if (flat < 256) {
    B1c2[(flat - 128) * 256 + tid] = B1_2[(flat - 128) * 256 + tid] * C2L;
  } else if (flat < 288) {
    out[(flat - 256) * 256 + tid] = bout[0];
  }

  const int n  = bx * 64 + lane;
  const int j0 = by * 16 + wave * 4;
  const float hx = x[n], ht = t[n];
#pragma unroll
  for (int jj = 0; jj < 4; ++jj) {
    const int j = j0 + jj;
    float a0 = B2[j * 2 + 0];
    float a1 = B2[j * 2 + 1];
#pragma unroll
    for (int k = 0; k < 8; ++k) {
      float z0 = fmaf(hx, W1[j * 16 + k], B1[j * 16 + k]);
      a0 = fmaf(W2[j * 16 + k], tanh_hw(z0), a0);
      float z1 = fmaf(ht, W1[j * 16 + 8 + k], B1[j * 16 + 8 + k]);
      a1 = fmaf(W2[j * 16 + 8 + k], tanh_hw(z1), a1);
    }
    float y = a0 + a1;
    float e = __builtin_amdgcn_exp2f(y * C2L);
    float r = __builtin_amdgcn_rcpf(1.0f + e);
    hA[j * 8192 + n] = fmaf(r, -2.f * C2L, C2L);   // C2L * tanh(y)
  }
}

// ---------------- K1: layer1 (float4 weight-load arm) ----------------
__global__ __launch_bounds__(256, 8) void kan_layer1(
    const float* __restrict__ hin,   // [64][8192] = C2L * h0
    const float* __restrict__ W1,    // (64,64,8)
    const float* __restrict__ B1c,   // (64,64,8) = C2L * B1
    const float* __restrict__ W2,    // (64,64,8)
    const float* __restrict__ B2,    // (64,64)
    float* __restrict__ hout)        // [64][8192] = C2L * h1
{
  __shared__ float hs[64][64];
  const int tid  = threadIdx.x;
  const int lane = tid & 63;
  const int wave = __builtin_amdgcn_readfirstlane(tid >> 6);
  const int n    = blockIdx.x * 64 + lane;

#pragma unroll
  for (int r = 0; r < 16; ++r) {
    const int i = r * 4 + wave;
    hs[i][lane] = hin[i * 8192 + n];
  }
  __syncthreads();

  const int j = blockIdx.y * 4 + wave;
  const float4* __restrict__ w1q = (const float4*)(W1  + j * 512);
  const float4* __restrict__ b1q = (const float4*)(B1c + j * 512);
  const float4* __restrict__ w2q = (const float4*)(W2  + j * 512);

  // S = sum(B2 row) + sum(W2 row)
  float sp = B2[j * 64 + lane];
  {
    const float4 va = w2q[lane * 2 + 0];
    const float4 vb = w2q[lane * 2 + 1];
    sp += (va.x + va.y) + (va.z + va.w) + (vb.x + vb.y) + (vb.z + vb.w);
  }
#pragma unroll
  for (int off = 32; off; off >>= 1) sp += __shfl_xor(sp, off);
  const float S = sp;

  float acc0 = 0.f, acc1 = 0.f, acc2 = 0.f, acc3 = 0.f;
#pragma unroll 1
  for (int i = 0; i < 64; ++i) {
    const float hc = hs[i][lane];
    const float4 wa = w1q[i * 2 + 0];
    const float4 wb = w1q[i * 2 + 1];
    const float4 ba = b1q[i * 2 + 0];
    const float4 bb = b1q[i * 2 + 1];
    const float4 ca = w2q[i * 2 + 0];
    const float4 cb = w2q[i * 2 + 1];

    float z0 = fmaf(hc, wa.x, ba.x);
    float z1 = fmaf(hc, wa.y, ba.y);
    float z2 = fmaf(hc, wa.z, ba.z);
    float z3 = fmaf(hc, wa.w, ba.w);
    float z4 = fmaf(hc, wb.x, bb.x);
    float z5 = fmaf(hc, wb.y, bb.y);
    float z6 = fmaf(hc, wb.z, bb.z);
    float z7 = fmaf(hc, wb.w, bb.w);
    float s0 = __builtin_amdgcn_rcpf(1.0f + __builtin_amdgcn_exp2f(z0));
    float s1 = __builtin_amdgcn_rcpf(1.0f + __builtin_amdgcn_exp2f(z1));
    float s2 = __builtin_amdgcn_rcpf(1.0f + __builtin_amdgcn_exp2f(z2));
    float s3 = __builtin_amdgcn_rcpf(1.0f + __builtin_amdgcn_exp2f(z3));
    float s4 = __builtin_amdgcn_rcpf(1.0f + __builtin_amdgcn_exp2f(z4));
    float s5 = __builtin_amdgcn_rcpf(1.0f + __builtin_amdgcn_exp2f(z5));
    float s6 = __builtin_amdgcn_rcpf(1.0f + __builtin_amdgcn_exp2f(z6));
    float s7 = __builtin_amdgcn_rcpf(1.0f + __builtin_amdgcn_exp2f(z7));
    acc0 = fmaf(ca.x, s0, acc0);
    acc1 = fmaf(ca.y, s1, acc1);
    acc2 = fmaf(ca.z, s2, acc2);
    acc3 = fmaf(ca.w, s3, acc3);
    acc0 = fmaf(cb.x, s4, acc0);
    acc1 = fmaf(cb.y, s5, acc1);
    acc2 = fmaf(cb.z, s6, acc2);
    acc3 = fmaf(cb.w, s7, acc3);
  }

  const float y = S - 2.f * ((acc0 + acc1) + (acc2 + acc3));
  const float e = __builtin_amdgcn_exp2f(y * C2L);
  const float r = __builtin_amdgcn_rcpf(1.0f + e);
  hout[j * 8192 + n] = fmaf(r, -2.f * C2L, C2L);   // C2L * tanh(y)
}

// ---------------- K2: layer2 + head (scalar-load control, hw rcp) ----------------
__global__ __launch_bounds__(256, 8) void kan_layer2(
    const float* __restrict__ hin,   // [64][8192] = C2L * h1
    const float* __restrict__ W1,    // (64,64,8)
    const float* __restrict__ B1c,   // (64,64,8) = C2L * B1
    const float* __restrict__ W2,    // (64,64,8)
    const float* __restrict__ B2,    // (64,64)
    const float* __restrict__ Wout,  // (1,64)
    float* __restrict__ out)         // (8192,) += partials
{
  __shared__ float hs[64][64];
  __shared__ float red[4][64];
  const int tid  = threadIdx.x;
  const int lane = tid & 63;
  const int wave = __builtin_amdgcn_readfirstlane(tid >> 6);
  const int n    = blockIdx.x * 64 + lane;

#pragma unroll
  for (int r = 0; r < 16; ++r) {
    const int i = r * 4 + wave;
    hs[i][lane] = hin[i * 8192 + n];
  }
  __syncthreads();

  const int j = blockIdx.y * 4 + wave;
  const float* __restrict__ w1p = W1  + j * 512;
  const float* __restrict__ b1p = B1c + j * 512;
  const float* __restrict__ w2p = W2  + j * 512;

  // S = sum(B2 row) + sum(W2 row)
  float sp = B2[j * 64 + lane];
  {
    const float4* w2v = (const float4*)w2p;
    const float4 va = w2v[lane * 2 + 0];
    const float4 vb = w2v[lane * 2 + 1];
    sp += (va.x + va.y) + (va.z + va.w) + (vb.x + vb.y) + (vb.z + vb.w);
  }
#pragma unroll
  for (int off = 32; off; off >>= 1) sp += __shfl_xor(sp, off);
  const float S = sp;

  float acc0 = 0.f, acc1 = 0.f, acc2 = 0.f, acc3 = 0.f;
  for (int i = 0; i < 64; ++i) {
    const float hc = hs[i][lane];
    const int base = i * 8;
#pragma unroll
    for (int k = 0; k < 8; k += 4) {
      float z0 = fmaf(hc, w1p[base + k + 0], b1p[base + k + 0]);
      float z1 = fmaf(hc, w1p[base + k + 1], b1p[base + k + 1]);
      float z2 = fmaf(hc, w1p[base + k + 2], b1p[base + k + 2]);
      float z3 = fmaf(hc, w1p[base + k + 3], b1p[base + k + 3]);
      float s0 = __builtin_amdgcn_rcpf(1.0f + __builtin_amdgcn_exp2f(z0));
      float s1 = __builtin_amdgcn_rcpf(1.0f + __builtin_amdgcn_exp2f(z1));
      float s2 = __builtin_amdgcn_rcpf(1.0f + __builtin_amdgcn_exp2f(z2));
      float s3 = __builtin_amdgcn_rcpf(1.0f + __builtin_amdgcn_exp2f(z3));
      acc0 = fmaf(w2p[base + k + 0], s0, acc0);
      acc1 = fmaf(w2p[base + k + 1], s1, acc1);
      acc2 = fmaf(w2p[base + k + 2], s2, acc2);
      acc3 = fmaf(w2p[base + k + 3], s3, acc3);
    }
  }

  const float y = S - 2.f * ((acc0 + acc1) + (acc2 + acc3));
  const float e = __builtin_amdgcn_exp2f(y * C2L);
  const float r = __builtin_amdgcn_rcpf(1.0f + e);
  const float h2 = fmaf(r, -2.f, 1.f);           // tanh(y)

  red[wave][lane] = h2 * Wout[j];
  __syncthreads();
  if (wave == 0) {
    const float pblk = (red[0][lane] + red[1][lane]) + (red[2][lane] + red[3][lane]);
    atomicAdd(&out[n], pblk);
  }
}

extern "C" void kernel_launch(void* const* d_in, const int* in_sizes, int n_in,
                              void* d_out, int out_size, void* d_ws, size_t ws_size,
                              hipStream_t stream) {
  const float* x    = (const float*)d_in[0];
  const float* t    = (const float*)d_in[1];
  const float* W1_0 = (const float*)d_in[2];
  const float* B1_0 = (const float*)d_in[3];
  const float* W2_0 = (const float*)d_in[4];
  const float* B2_0 = (const float*)d_in[5];
  const float* W1_1 = (const float*)d_in[6];
  const float* B1_1 = (const float*)d_in[7];
  const float* W2_1 = (const float*)d_in[8];
  const float* B2_1 = (const float*)d_in[9];
  const float* W1_2 = (const float*)d_in[10];
  const float* B1_2 = (const float*)d_in[11];
  const float* W2_2 = (const float*)d_in[12];
  const float* B2_2 = (const float*)d_in[13];
  const float* Wout = (const float*)d_in[14];
  const float* bout = (const float*)d_in[15];
  float* out = (float*)d_out;

  float* hA   = (float*)d_ws;          // [64][8192] = 2 MB
  float* hB   = hA + 64 * 8192;        // [64][8192] = 2 MB
  float* B1c1 = hB + 64 * 8192;        // 32768 floats
  float* B1c2 = B1c1 + 32768;          // 32768 floats

  kan_layer0<<<dim3(128, 4), 256, 0, stream>>>(
      x, t, W1_0, B1_0, W2_0, B2_0, B1_1, B1_2, bout, hA, B1c1, B1c2, out);
  kan_layer1<<<dim3(128, 16), 256, 0, stream>>>(hA, W1_1, B1c1, W2_1, B2_1, hB);
  kan_layer2<<<dim3(128, 16), 256, 0, stream>>>(hB, W1_2, B1c2, W2_2, B2_2, Wout, out);
}

// Round 10
// 153.461 us; speedup vs baseline: 1.6906x; 1.3495x over previous
//
#include <hip/hip_runtime.h>
#include <math.h>

// KAN-PINN forward, MI355X — round 10: Chebyshev factorization.
// For layers 1,2: f_{j,i}(h) = sum_k W2*tanh(W1*h+B1) + B2 is smooth on h in [-1,1]
// (h is a tanh output). Expand in T_p(h), P=20 terms (coeff decay rho^-p, rho~1.9
// at max|W1|~2.3 -> tail <= ~4e-4 worst triple). Layer = pure fp32 FMA contraction
// y[n,j] = sum_{i,p} G[j,i,p] T_p(h[n,i]); T_p by recurrence. No transcendentals.
// Prep kernel builds G via 32-pt Gauss-Chebyshev DCT (B2 folded into p=0).

#define C2L 2.88539008177792681472f  // 2*log2(e)
#define P_CHEB 20
#define M_SAMP 32

__device__ __forceinline__ float tanh_hw(float z) {
  float e = __builtin_amdgcn_exp2f(z * C2L);
  float r = __builtin_amdgcn_rcpf(1.0f + e);
  return fmaf(r, -2.0f, 1.0f);
}

// ---------------- PREP: G[j][i][p] for both big layers ----------------
// one thread per (layer, j*64+i, k); k = low 3 lane bits -> shfl reduce.
__global__ __launch_bounds__(256) void kan_prep(
    const float* __restrict__ W1_1, const float* __restrict__ B1_1,
    const float* __restrict__ W2_1, const float* __restrict__ B2_1,
    const float* __restrict__ W1_2, const float* __restrict__ B1_2,
    const float* __restrict__ W2_2, const float* __restrict__ B2_2,
    float* __restrict__ G1, float* __restrict__ G2)
{
  const int g = blockIdx.x * 256 + threadIdx.x;
  const int k = g & 7;
  const int ji = (g >> 3) & 4095;
  const int layer = g >> 15;                  // 0 or 1
  const float* __restrict__ W1 = layer ? W1_2 : W1_1;
  const float* __restrict__ B1 = layer ? B1_2 : B1_1;
  const float* __restrict__ W2 = layer ? W2_2 : W2_1;
  const float* __restrict__ B2 = layer ? B2_2 : B2_1;
  float* __restrict__ G = layer ? G2 : G1;

  const float w  = W1[ji * 8 + k];
  const float b  = B1[ji * 8 + k];
  const float w2 = W2[ji * 8 + k];

  float acc[P_CHEB];
#pragma unroll
  for (int p = 0; p < P_CHEB; ++p) acc[p] = 0.f;

  for (int m = 0; m < M_SAMP; ++m) {
    const float theta = ((float)m + 0.5f) * (3.14159265358979323846f / M_SAMP);
    const float c = cosf(theta);                    // sample x in (-1,1)
    const float s = w2 * tanh_hw(fmaf(w, c, b));    // W2 * tanh(W1*x+B1)
    acc[0] += s;
    acc[1] = fmaf(s, c, acc[1]);
    const float c2 = c + c;
    float tp0 = 1.f, tp1 = c;
#pragma unroll
    for (int p = 2; p < P_CHEB; ++p) {
      const float t = fmaf(c2, tp1, -tp0);
      acc[p] = fmaf(s, t, acc[p]);
      tp0 = tp1; tp1 = t;
    }
  }
#pragma unroll
  for (int p = 0; p < P_CHEB; ++p) {
    float v = acc[p] * ((p == 0) ? (1.f / M_SAMP) : (2.f / M_SAMP));
    v += __shfl_xor(v, 1);
    v += __shfl_xor(v, 2);
    v += __shfl_xor(v, 4);                          // sum over k (8 lanes)
    acc[p] = v;
  }
  if (k == 0) {
    float* __restrict__ dst = G + ji * P_CHEB;
    acc[0] += B2[ji];                               // fold B2 into T_0 term
#pragma unroll
    for (int p = 0; p < P_CHEB; ++p) dst[p] = acc[p];
  }
}

// ---------------- K0: layer0 (exact tanh path, d_in=2) + out init ----------------
__global__ __launch_bounds__(256) void kan_layer0(
    const float* __restrict__ x, const float* __restrict__ t,
    const float* __restrict__ W1, const float* __restrict__ B1,   // (64,2,8)
    const float* __restrict__ W2, const float* __restrict__ B2,   // (64,2,8),(64,2)
    const float* __restrict__ bout,
    float* __restrict__ hA,      // [64][8192] = h0 (unscaled tanh)
    float* __restrict__ out)     // (8192,) <- b_out
{
  const int tid  = threadIdx.x;
  const int lane = tid & 63;
  const int wave = __builtin_amdgcn_readfirstlane(tid >> 6);
  const int bx = blockIdx.x, by = blockIdx.y;
  const int flat = by * 128 + bx;
  if (flat < 32) out[flat * 256 + tid] = bout[0];

  const int n  = bx * 64 + lane;
  const int j0 = by * 16 + wave * 4;
  const float hx = x[n], ht = t[n];
#pragma unroll
  for (int jj = 0; jj < 4; ++jj) {
    const int j = j0 + jj;
    float a0 = B2[j * 2 + 0];
    float a1 = B2[j * 2 + 1];
#pragma unroll
    for (int k = 0; k < 8; ++k) {
      float z0 = fmaf(hx, W1[j * 16 + k], B1[j * 16 + k]);
      a0 = fmaf(W2[j * 16 + k], tanh_hw(z0), a0);
      float z1 = fmaf(ht, W1[j * 16 + 8 + k], B1[j * 16 + 8 + k]);
      a1 = fmaf(W2[j * 16 + 8 + k], tanh_hw(z1), a1);
    }
    hA[j * 8192 + n] = tanh_hw(a0 + a1);
  }
}

// ---------------- K1/K2: Chebyshev layer (HEAD=1 fuses output head) ----------------
// grid (128, 8), block 256 (4 waves); wave handles jA = by*8 + wave*2 and jA+1.
template <int HEAD>
__global__ __launch_bounds__(256, 4) void kan_cheb(
    const float* __restrict__ hin,   // [64][8192], |h|<=1
    const float* __restrict__ G,     // [64][64][P_CHEB]
    const float* __restrict__ Wout,  // (1,64) if HEAD
    float* __restrict__ outp)        // hout [64][8192] or out (8192,)
{
  __shared__ float hs[64][64];
  __shared__ float red[4][64];
  const int tid  = threadIdx.x;
  const int lane = tid & 63;
  const int wave = __builtin_amdgcn_readfirstlane(tid >> 6);
  const int n    = blockIdx.x * 64 + lane;

#pragma unroll
  for (int r = 0; r < 16; ++r) {
    const int i = r * 4 + wave;
    hs[i][lane] = hin[i * 8192 + n];
  }
  __syncthreads();

  const int jA = blockIdx.y * 8 + wave * 2;
  const float4* __restrict__ gaq = (const float4*)(G + jA * (64 * P_CHEB));
  const float4* __restrict__ gbq = (const float4*)(G + (jA + 1) * (64 * P_CHEB));

  float aA0 = 0.f, aA1 = 0.f, aB0 = 0.f, aB1 = 0.f;  // even/odd-p split chains
  for (int i = 0; i < 64; ++i) {
    const float h  = hs[i][lane];
    const float h2 = h + h;
    float ga[P_CHEB], gb[P_CHEB];
#pragma unroll
    for (int q = 0; q < P_CHEB / 4; ++q) {
      const float4 va = gaq[i * (P_CHEB / 4) + q];
      ga[4 * q + 0] = va.x; ga[4 * q + 1] = va.y; ga[4 * q + 2] = va.z; ga[4 * q + 3] = va.w;
      const float4 vb = gbq[i * (P_CHEB / 4) + q];
      gb[4 * q + 0] = vb.x; gb[4 * q + 1] = vb.y; gb[4 * q + 2] = vb.z; gb[4 * q + 3] = vb.w;
    }
    aA0 += ga[0];  aB0 += gb[0];                 // p=0 (T_0 = 1)
    aA1 = fmaf(ga[1], h, aA1);                   // p=1 (T_1 = h)
    aB1 = fmaf(gb[1], h, aB1);
    float tp0 = 1.f, tp1 = h;
#pragma unroll
    for (int p = 2; p < P_CHEB; ++p) {
      const float tc = fmaf(h2, tp1, -tp0);      // T_p = 2h*T_{p-1} - T_{p-2}
      if (p & 1) { aA1 = fmaf(ga[p], tc, aA1); aB1 = fmaf(gb[p], tc, aB1); }
      else       { aA0 = fmaf(ga[p], tc, aA0); aB0 = fmaf(gb[p], tc, aB0); }
      tp0 = tp1; tp1 = tc;
    }
  }
  const float yA = aA0 + aA1;
  const float yB = aB0 + aB1;

  if (HEAD) {
    red[wave][lane] = tanh_hw(yA) * Wout[jA] + tanh_hw(yB) * Wout[jA + 1];
    __syncthreads();
    if (wave == 0) {
      atomicAdd(&outp[n], (red[0][lane] + red[1][lane]) + (red[2][lane] + red[3][lane]));
    }
  } else {
    outp[jA * 8192 + n]       = tanh_hw(yA);
    outp[(jA + 1) * 8192 + n] = tanh_hw(yB);
  }
}

extern "C" void kernel_launch(void* const* d_in, const int* in_sizes, int n_in,
                              void* d_out, int out_size, void* d_ws, size_t ws_size,
                              hipStream_t stream) {
  const float* x    = (const float*)d_in[0];
  const float* t    = (const float*)d_in[1];
  const float* W1_0 = (const float*)d_in[2];
  const float* B1_0 = (const float*)d_in[3];
  const float* W2_0 = (const float*)d_in[4];
  const float* B2_0 = (const float*)d_in[5];
  const float* W1_1 = (const float*)d_in[6];
  const float* B1_1 = (const float*)d_in[7];
  const float* W2_1 = (const float*)d_in[8];
  const float* B2_1 = (const float*)d_in[9];
  const float* W1_2 = (const float*)d_in[10];
  const float* B1_2 = (const float*)d_in[11];
  const float* W2_2 = (const float*)d_in[12];
  const float* B2_2 = (const float*)d_in[13];
  const float* Wout = (const float*)d_in[14];
  const float* bout = (const float*)d_in[15];
  float* out = (float*)d_out;

  float* hA = (float*)d_ws;                  // 512K floats (2 MB)
  float* hB = hA + 64 * 8192;                // 512K floats (2 MB)
  float* G1 = hB + 64 * 8192;                // 64*64*20 = 81920 floats (320 KB)
  float* G2 = G1 + 64 * 64 * P_CHEB;         // 81920 floats (320 KB)

  kan_prep<<<dim3(256), 256, 0, stream>>>(
      W1_1, B1_1, W2_1, B2_1, W1_2, B1_2, W2_2, B2_2, G1, G2);
  kan_layer0<<<dim3(128, 4), 256, 0, stream>>>(
      x, t, W1_0, B1_0, W2_0, B2_0, bout, hA, out);
  kan_cheb<0><<<dim3(128, 8), 256, 0, stream>>>(hA, G1, Wout, hB);
  kan_cheb<1><<<dim3(128, 8), 256, 0, stream>>>(hB, G2, Wout, out);
}

// Round 12
// 145.958 us; speedup vs baseline: 1.7775x; 1.0514x over previous
//
#include <hip/hip_runtime.h>
#include <math.h>

// KAN-PINN forward, MI355X — round 12 (= round 11 resubmitted; broker timeout).
// r10 Chebyshev factorization + : P=16, shallow product tree (depth 4 vs 18-serial
// recurrence), 512-thr/8-wave cheb blocks with i-split (32 waves/CU = 8/SIMD).
// y[n,j] = sum_{i,p} G[j,i,p] T_p(h[n,i]);  G built in prep via 32-pt Gauss-Cheb DCT.

#define C2L 2.88539008177792681472f  // 2*log2(e)
#define P_CHEB 16
#define M_SAMP 32

__device__ __forceinline__ float tanh_hw(float z) {
  float e = __builtin_amdgcn_exp2f(z * C2L);
  float r = __builtin_amdgcn_rcpf(1.0f + e);
  return fmaf(r, -2.0f, 1.0f);
}

// ---------------- PREP: G[j][i][p] for both big layers ----------------
__global__ __launch_bounds__(256) void kan_prep(
    const float* __restrict__ W1_1, const float* __restrict__ B1_1,
    const float* __restrict__ W2_1, const float* __restrict__ B2_1,
    const float* __restrict__ W1_2, const float* __restrict__ B1_2,
    const float* __restrict__ W2_2, const float* __restrict__ B2_2,
    float* __restrict__ G1, float* __restrict__ G2)
{
  const int g = blockIdx.x * 256 + threadIdx.x;
  const int k = g & 7;
  const int ji = (g >> 3) & 4095;
  const int layer = g >> 15;                  // 0 or 1
  const float* __restrict__ W1 = layer ? W1_2 : W1_1;
  const float* __restrict__ B1 = layer ? B1_2 : B1_1;
  const float* __restrict__ W2 = layer ? W2_2 : W2_1;
  const float* __restrict__ B2 = layer ? B2_2 : B2_1;
  float* __restrict__ G = layer ? G2 : G1;

  const float w  = W1[ji * 8 + k];
  const float b  = B1[ji * 8 + k];
  const float w2 = W2[ji * 8 + k];

  float acc[P_CHEB];
#pragma unroll
  for (int p = 0; p < P_CHEB; ++p) acc[p] = 0.f;

  for (int m = 0; m < M_SAMP; ++m) {
    const float theta = ((float)m + 0.5f) * (3.14159265358979323846f / M_SAMP);
    const float c = cosf(theta);
    const float s = w2 * tanh_hw(fmaf(w, c, b));
    acc[0] += s;
    acc[1] = fmaf(s, c, acc[1]);
    const float c2 = c + c;
    float tp0 = 1.f, tp1 = c;
#pragma unroll
    for (int p = 2; p < P_CHEB; ++p) {
      const float t = fmaf(c2, tp1, -tp0);
      acc[p] = fmaf(s, t, acc[p]);
      tp0 = tp1; tp1 = t;
    }
  }
#pragma unroll
  for (int p = 0; p < P_CHEB; ++p) {
    float v = acc[p] * ((p == 0) ? (1.f / M_SAMP) : (2.f / M_SAMP));
    v += __shfl_xor(v, 1);
    v += __shfl_xor(v, 2);
    v += __shfl_xor(v, 4);                    // sum over k
    acc[p] = v;
  }
  if (k == 0) {
    float* __restrict__ dst = G + ji * P_CHEB;
    acc[0] += B2[ji];                         // fold B2 into T_0
#pragma unroll
    for (int p = 0; p < P_CHEB; ++p) dst[p] = acc[p];
  }
}

// ---------------- K0: layer0 (exact path, d_in=2) + out init ----------------
// grid (128,16), block 256: wave handles ONE j (17 tanh/lane). 32 waves/CU.
__global__ __launch_bounds__(256) void kan_layer0(
    const float* __restrict__ x, const float* __restrict__ t,
    const float* __restrict__ W1, const float* __restrict__ B1,   // (64,2,8)
    const float* __restrict__ W2, const float* __restrict__ B2,   // (64,2,8),(64,2)
    const float* __restrict__ bout,
    float* __restrict__ hA,      // [64][8192] = h0
    float* __restrict__ out)     // (8192,) <- b_out
{
  const int tid  = threadIdx.x;
  const int lane = tid & 63;
  const int wave = __builtin_amdgcn_readfirstlane(tid >> 6);
  const int bx = blockIdx.x, by = blockIdx.y;
  const int flat = by * 128 + bx;
  if (flat < 32) out[flat * 256 + tid] = bout[0];

  const int n = bx * 64 + lane;
  const int j = by * 4 + wave;
  const float hx = x[n], ht = t[n];
  float a0 = B2[j * 2 + 0];
  float a1 = B2[j * 2 + 1];
#pragma unroll
  for (int k = 0; k < 8; ++k) {
    float z0 = fmaf(hx, W1[j * 16 + k], B1[j * 16 + k]);
    a0 = fmaf(W2[j * 16 + k], tanh_hw(z0), a0);
    float z1 = fmaf(ht, W1[j * 16 + 8 + k], B1[j * 16 + 8 + k]);
    a1 = fmaf(W2[j * 16 + 8 + k], tanh_hw(z1), a1);
  }
  hA[j * 8192 + n] = tanh_hw(a0 + a1);
}

// ---------------- cheb layer: 512 thr (8 waves), grid (128,8) ----------------
// wave w: jpair = by*4 + (w&3), ihalf = w>>2 -> i in [ihalf*32, ihalf*32+32).
// Shallow tree: T_{m+n} = 2 T_m T_n - T_{m-n}, depth 4.
template <int HEAD>
__global__ __launch_bounds__(512, 8) void kan_cheb(
    const float* __restrict__ hin,   // [64][8192], |h|<=1
    const float* __restrict__ G,     // [64][64][P_CHEB]
    const float* __restrict__ Wout,  // (1,64) if HEAD
    float* __restrict__ outp)        // hout [64][8192] or out (8192,)
{
  __shared__ float hs[64][64];       // 16 KB
  __shared__ float redA[8][64];      // 2 KB
  __shared__ float redB[8][64];      // 2 KB
  const int tid  = threadIdx.x;
  const int lane = tid & 63;
  const int wave = __builtin_amdgcn_readfirstlane(tid >> 6);
  const int n    = blockIdx.x * 64 + lane;

#pragma unroll
  for (int r = 0; r < 8; ++r) {
    const int i = r * 8 + wave;
    hs[i][lane] = hin[i * 8192 + n];
  }
  __syncthreads();

  const int jA = (blockIdx.y * 4 + (wave & 3)) * 2;
  const int jB = jA + 1;
  const int ihalf = wave >> 2;
  const float4* __restrict__ gaq = (const float4*)(G + jA * (64 * P_CHEB));
  const float4* __restrict__ gbq = (const float4*)(G + jB * (64 * P_CHEB));

  float aA0 = 0.f, aA1 = 0.f, aB0 = 0.f, aB1 = 0.f;
  const int i0 = ihalf * 32;
  for (int i = i0; i < i0 + 32; ++i) {
    const float h  = hs[i][lane];
    const float h2 = h + h;
    // ---- shallow Chebyshev tree, T_2..T_15, depth 4 ----
    const float t2  = fmaf(h2, h,  -1.f);
    const float d2  = t2 + t2;
    const float t3  = fmaf(h2, t2, -h);
    const float t4  = fmaf(d2, t2, -1.f);
    const float d3  = t3 + t3;
    const float d4  = t4 + t4;
    const float t5  = fmaf(d3, t2, -h);
    const float t6  = fmaf(d3, t3, -1.f);
    const float t7  = fmaf(d4, t3, -h);
    const float t8  = fmaf(d4, t4, -1.f);
    const float d5  = t5 + t5;
    const float d6  = t6 + t6;
    const float d7  = t7 + t7;
    const float d8  = t8 + t8;
    const float t9  = fmaf(d5, t4, -h);
    const float t10 = fmaf(d5, t5, -1.f);
    const float t11 = fmaf(d6, t5, -h);
    const float t12 = fmaf(d6, t6, -1.f);
    const float t13 = fmaf(d7, t6, -h);
    const float t14 = fmaf(d7, t7, -1.f);
    const float t15 = fmaf(d8, t7, -h);

    const float4 va0 = gaq[i * 4 + 0];
    const float4 va1 = gaq[i * 4 + 1];
    const float4 va2 = gaq[i * 4 + 2];
    const float4 va3 = gaq[i * 4 + 3];
    aA0 += va0.x;
    aA1 = fmaf(va0.y, h,   aA1);
    aA0 = fmaf(va0.z, t2,  aA0);
    aA1 = fmaf(va0.w, t3,  aA1);
    aA0 = fmaf(va1.x, t4,  aA0);
    aA1 = fmaf(va1.y, t5,  aA1);
    aA0 = fmaf(va1.z, t6,  aA0);
    aA1 = fmaf(va1.w, t7,  aA1);
    aA0 = fmaf(va2.x, t8,  aA0);
    aA1 = fmaf(va2.y, t9,  aA1);
    aA0 = fmaf(va2.z, t10, aA0);
    aA1 = fmaf(va2.w, t11, aA1);
    aA0 = fmaf(va3.x, t12, aA0);
    aA1 = fmaf(va3.y, t13, aA1);
    aA0 = fmaf(va3.z, t14, aA0);
    aA1 = fmaf(va3.w, t15, aA1);

    const float4 vb0 = gbq[i * 4 + 0];
    const float4 vb1 = gbq[i * 4 + 1];
    const float4 vb2 = gbq[i * 4 + 2];
    const float4 vb3 = gbq[i * 4 + 3];
    aB0 += vb0.x;
    aB1 = fmaf(vb0.y, h,   aB1);
    aB0 = fmaf(vb0.z, t2,  aB0);
    aB1 = fmaf(vb0.w, t3,  aB1);
    aB0 = fmaf(vb1.x, t4,  aB0);
    aB1 = fmaf(vb1.y, t5,  aB1);
    aB0 = fmaf(vb1.z, t6,  aB0);
    aB1 = fmaf(vb1.w, t7,  aB1);
    aB0 = fmaf(vb2.x, t8,  aB0);
    aB1 = fmaf(vb2.y, t9,  aB1);
    aB0 = fmaf(vb2.z, t10, aB0);
    aB1 = fmaf(vb2.w, t11, aB1);
    aB0 = fmaf(vb3.x, t12, aB0);
    aB1 = fmaf(vb3.y, t13, aB1);
    aB0 = fmaf(vb3.z, t14, aB0);
    aB1 = fmaf(vb3.w, t15, aB1);
  }

  redA[wave][lane] = aA0 + aA1;
  redB[wave][lane] = aB0 + aB1;
  __syncthreads();

  if (HEAD) {
    if (wave < 4) {
      const float yA = redA[wave][lane] + redA[wave + 4][lane];
      const float yB = redB[wave][lane] + redB[wave + 4][lane];
      redA[wave][lane] = tanh_hw(yA) * Wout[jA] + tanh_hw(yB) * Wout[jB];
    }
    __syncthreads();
    if (wave == 0) {
      atomicAdd(&outp[n], (redA[0][lane] + redA[1][lane]) +
                          (redA[2][lane] + redA[3][lane]));
    }
  } else {
    if (wave < 4) {
      const float yA = redA[wave][lane] + redA[wave + 4][lane];
      const float yB = redB[wave][lane] + redB[wave + 4][lane];
      outp[jA * 8192 + n] = tanh_hw(yA);
      outp[jB * 8192 + n] = tanh_hw(yB);
    }
  }
}

extern "C" void kernel_launch(void* const* d_in, const int* in_sizes, int n_in,
                              void* d_out, int out_size, void* d_ws, size_t ws_size,
                              hipStream_t stream) {
  const float* x    = (const float*)d_in[0];
  const float* t    = (const float*)d_in[1];
  const float* W1_0 = (const float*)d_in[2];
  const float* B1_0 = (const float*)d_in[3];
  const float* W2_0 = (const float*)d_in[4];
  const float* B2_0 = (const float*)d_in[5];
  const float* W1_1 = (const float*)d_in[6];
  const float* B1_1 = (const float*)d_in[7];
  const float* W2_1 = (const float*)d_in[8];
  const float* B2_1 = (const float*)d_in[9];
  const float* W1_2 = (const float*)d_in[10];
  const float* B1_2 = (const float*)d_in[11];
  const float* W2_2 = (const float*)d_in[12];
  const float* B2_2 = (const float*)d_in[13];
  const float* Wout = (const float*)d_in[14];
  const float* bout = (const float*)d_in[15];
  float* out = (float*)d_out;

  float* hA = (float*)d_ws;                  // 2 MB
  float* hB = hA + 64 * 8192;                // 2 MB
  float* G1 = hB + 64 * 8192;                // 64*64*16 floats (256 KB)
  float* G2 = G1 + 64 * 64 * P_CHEB;         // 256 KB

  kan_prep<<<dim3(256), 256, 0, stream>>>(
      W1_1, B1_1, W2_1, B2_1, W1_2, B1_2, W2_2, B2_2, G1, G2);
  kan_layer0<<<dim3(128, 16), 256, 0, stream>>>(
      x, t, W1_0, B1_0, W2_0, B2_0, bout, hA, out);
  kan_cheb<0><<<dim3(128, 8), 512, 0, stream>>>(hA, G1, Wout, hB);
  kan_cheb<1><<<dim3(128, 8), 512, 0, stream>>>(hB, G2, Wout, out);
}

// Round 14
// 141.015 us; speedup vs baseline: 1.8398x; 1.0351x over previous
//
#include <hip/hip_runtime.h>
#include <math.h>

// KAN-PINN forward, MI355X — round 14 (= round 13 resubmitted; broker timeout).
// r12 + G routed through LDS: per-block 32KB G-slab staged coalesced, inner-loop
// G reads are ds_read_b128 broadcast (uniform addr) on the LDS pipe -> overlaps
// VALU, removing the s_load/K$ serialization (theory for r12's 35us/layer).

#define C2L 2.88539008177792681472f  // 2*log2(e)
#define P_CHEB 16
#define M_SAMP 32

__device__ __forceinline__ float tanh_hw(float z) {
  float e = __builtin_amdgcn_exp2f(z * C2L);
  float r = __builtin_amdgcn_rcpf(1.0f + e);
  return fmaf(r, -2.0f, 1.0f);
}

// ---------------- PREP: G[j][i][p] for both big layers ----------------
__global__ __launch_bounds__(256) void kan_prep(
    const float* __restrict__ W1_1, const float* __restrict__ B1_1,
    const float* __restrict__ W2_1, const float* __restrict__ B2_1,
    const float* __restrict__ W1_2, const float* __restrict__ B1_2,
    const float* __restrict__ W2_2, const float* __restrict__ B2_2,
    float* __restrict__ G1, float* __restrict__ G2)
{
  const int g = blockIdx.x * 256 + threadIdx.x;
  const int k = g & 7;
  const int ji = (g >> 3) & 4095;
  const int layer = g >> 15;                  // 0 or 1
  const float* __restrict__ W1 = layer ? W1_2 : W1_1;
  const float* __restrict__ B1 = layer ? B1_2 : B1_1;
  const float* __restrict__ W2 = layer ? W2_2 : W2_1;
  const float* __restrict__ B2 = layer ? B2_2 : B2_1;
  float* __restrict__ G = layer ? G2 : G1;

  const float w  = W1[ji * 8 + k];
  const float b  = B1[ji * 8 + k];
  const float w2 = W2[ji * 8 + k];

  float acc[P_CHEB];
#pragma unroll
  for (int p = 0; p < P_CHEB; ++p) acc[p] = 0.f;

  for (int m = 0; m < M_SAMP; ++m) {
    const float theta = ((float)m + 0.5f) * (3.14159265358979323846f / M_SAMP);
    const float c = cosf(theta);
    const float s = w2 * tanh_hw(fmaf(w, c, b));
    acc[0] += s;
    acc[1] = fmaf(s, c, acc[1]);
    const float c2 = c + c;
    float tp0 = 1.f, tp1 = c;
#pragma unroll
    for (int p = 2; p < P_CHEB; ++p) {
      const float t = fmaf(c2, tp1, -tp0);
      acc[p] = fmaf(s, t, acc[p]);
      tp0 = tp1; tp1 = t;
    }
  }
#pragma unroll
  for (int p = 0; p < P_CHEB; ++p) {
    float v = acc[p] * ((p == 0) ? (1.f / M_SAMP) : (2.f / M_SAMP));
    v += __shfl_xor(v, 1);
    v += __shfl_xor(v, 2);
    v += __shfl_xor(v, 4);                    // sum over k
    acc[p] = v;
  }
  if (k == 0) {
    float* __restrict__ dst = G + ji * P_CHEB;
    acc[0] += B2[ji];                         // fold B2 into T_0
#pragma unroll
    for (int p = 0; p < P_CHEB; ++p) dst[p] = acc[p];
  }
}

// ---------------- K0: layer0 (exact path, d_in=2) + out init ----------------
__global__ __launch_bounds__(256) void kan_layer0(
    const float* __restrict__ x, const float* __restrict__ t,
    const float* __restrict__ W1, const float* __restrict__ B1,   // (64,2,8)
    const float* __restrict__ W2, const float* __restrict__ B2,   // (64,2,8),(64,2)
    const float* __restrict__ bout,
    float* __restrict__ hA,      // [64][8192] = h0
    float* __restrict__ out)     // (8192,) <- b_out
{
  const int tid  = threadIdx.x;
  const int lane = tid & 63;
  const int wave = __builtin_amdgcn_readfirstlane(tid >> 6);
  const int bx = blockIdx.x, by = blockIdx.y;
  const int flat = by * 128 + bx;
  if (flat < 32) out[flat * 256 + tid] = bout[0];

  const int n = bx * 64 + lane;
  const int j = by * 4 + wave;
  const float hx = x[n], ht = t[n];
  float a0 = B2[j * 2 + 0];
  float a1 = B2[j * 2 + 1];
#pragma unroll
  for (int k = 0; k < 8; ++k) {
    float z0 = fmaf(hx, W1[j * 16 + k], B1[j * 16 + k]);
    a0 = fmaf(W2[j * 16 + k], tanh_hw(z0), a0);
    float z1 = fmaf(ht, W1[j * 16 + 8 + k], B1[j * 16 + 8 + k]);
    a1 = fmaf(W2[j * 16 + 8 + k], tanh_hw(z1), a1);
  }
  hA[j * 8192 + n] = tanh_hw(a0 + a1);
}

// ---------------- cheb layer: 512 thr (8 waves), grid (128,8), G in LDS ----
// wave w: jpair local = (w&3)*2, ihalf = w>>2 -> i in [ihalf*32, ihalf*32+32).
template <int HEAD>
__global__ __launch_bounds__(512, 6) void kan_cheb(
    const float* __restrict__ hin,   // [64][8192], |h|<=1
    const float* __restrict__ G,     // [64][64][P_CHEB]
    const float* __restrict__ Wout,  // (1,64) if HEAD
    float* __restrict__ outp)        // hout [64][8192] or out (8192,)
{
  __shared__ float  hs[64][64];      // 16 KB
  __shared__ float4 Gs[8 * 256];     // 8 j x 64 i x 4 float4 = 32 KB
  __shared__ float  redA[8][64];     // 2 KB
  __shared__ float  redB[8][64];     // 2 KB
  const int tid  = threadIdx.x;
  const int lane = tid & 63;
  const int wave = __builtin_amdgcn_readfirstlane(tid >> 6);
  const int n    = blockIdx.x * 64 + lane;

#pragma unroll
  for (int r = 0; r < 8; ++r) {
    const int i = r * 8 + wave;
    hs[i][lane] = hin[i * 8192 + n];
  }
  // stage this block's 8-j G slab: 2048 float4, 512 threads -> 4 each, coalesced
  {
    const float4* __restrict__ gsrc = (const float4*)(G + blockIdx.y * 8 * 64 * P_CHEB);
#pragma unroll
    for (int q = 0; q < 4; ++q) Gs[q * 512 + tid] = gsrc[q * 512 + tid];
  }
  __syncthreads();

  const int jloc = (wave & 3) * 2;
  const int jA = blockIdx.y * 8 + jloc;
  const int jB = jA + 1;
  const int ihalf = wave >> 2;
  const float4* __restrict__ gaq = &Gs[jloc * 256];        // LDS, uniform addr
  const float4* __restrict__ gbq = &Gs[(jloc + 1) * 256];

  float aA0 = 0.f, aA1 = 0.f, aB0 = 0.f, aB1 = 0.f;
  const int i0 = ihalf * 32;
  for (int i = i0; i < i0 + 32; ++i) {
    const float h  = hs[i][lane];
    const float h2 = h + h;
    // ---- shallow Chebyshev tree, T_2..T_15, depth 4 ----
    const float t2  = fmaf(h2, h,  -1.f);
    const float d2  = t2 + t2;
    const float t3  = fmaf(h2, t2, -h);
    const float t4  = fmaf(d2, t2, -1.f);
    const float d3  = t3 + t3;
    const float d4  = t4 + t4;
    const float t5  = fmaf(d3, t2, -h);
    const float t6  = fmaf(d3, t3, -1.f);
    const float t7  = fmaf(d4, t3, -h);
    const float t8  = fmaf(d4, t4, -1.f);
    const float d5  = t5 + t5;
    const float d6  = t6 + t6;
    const float d7  = t7 + t7;
    const float d8  = t8 + t8;
    const float t9  = fmaf(d5, t4, -h);
    const float t10 = fmaf(d5, t5, -1.f);
    const float t11 = fmaf(d6, t5, -h);
    const float t12 = fmaf(d6, t6, -1.f);
    const float t13 = fmaf(d7, t6, -h);
    const float t14 = fmaf(d7, t7, -1.f);
    const float t15 = fmaf(d8, t7, -h);

    const float4 va0 = gaq[i * 4 + 0];
    const float4 va1 = gaq[i * 4 + 1];
    const float4 va2 = gaq[i * 4 + 2];
    const float4 va3 = gaq[i * 4 + 3];
    aA0 += va0.x;
    aA1 = fmaf(va0.y, h,   aA1);
    aA0 = fmaf(va0.z, t2,  aA0);
    aA1 = fmaf(va0.w, t3,  aA1);
    aA0 = fmaf(va1.x, t4,  aA0);
    aA1 = fmaf(va1.y, t5,  aA1);
    aA0 = fmaf(va1.z, t6,  aA0);
    aA1 = fmaf(va1.w, t7,  aA1);
    aA0 = fmaf(va2.x, t8,  aA0);
    aA1 = fmaf(va2.y, t9,  aA1);
    aA0 = fmaf(va2.z, t10, aA0);
    aA1 = fmaf(va2.w, t11, aA1);
    aA0 = fmaf(va3.x, t12, aA0);
    aA1 = fmaf(va3.y, t13, aA1);
    aA0 = fmaf(va3.z, t14, aA0);
    aA1 = fmaf(va3.w, t15, aA1);

    const float4 vb0 = gbq[i * 4 + 0];
    const float4 vb1 = gbq[i * 4 + 1];
    const float4 vb2 = gbq[i * 4 + 2];
    const float4 vb3 = gbq[i * 4 + 3];
    aB0 += vb0.x;
    aB1 = fmaf(vb0.y, h,   aB1);
    aB0 = fmaf(vb0.z, t2,  aB0);
    aB1 = fmaf(vb0.w, t3,  aB1);
    aB0 = fmaf(vb1.x, t4,  aB0);
    aB1 = fmaf(vb1.y, t5,  aB1);
    aB0 = fmaf(vb1.z, t6,  aB0);
    aB1 = fmaf(vb1.w, t7,  aB1);
    aB0 = fmaf(vb2.x, t8,  aB0);
    aB1 = fmaf(vb2.y, t9,  aB1);
    aB0 = fmaf(vb2.z, t10, aB0);
    aB1 = fmaf(vb2.w, t11, aB1);
    aB0 = fmaf(vb3.x, t12, aB0);
    aB1 = fmaf(vb3.y, t13, aB1);
    aB0 = fmaf(vb3.z, t14, aB0);
    aB1 = fmaf(vb3.w, t15, aB1);
  }

  redA[wave][lane] = aA0 + aA1;
  redB[wave][lane] = aB0 + aB1;
  __syncthreads();

  if (HEAD) {
    if (wave < 4) {
      const float yA = redA[wave][lane] + redA[wave + 4][lane];
      const float yB = redB[wave][lane] + redB[wave + 4][lane];
      redA[wave][lane] = tanh_hw(yA) * Wout[jA] + tanh_hw(yB) * Wout[jB];
    }
    __syncthreads();
    if (wave == 0) {
      atomicAdd(&outp[n], (redA[0][lane] + redA[1][lane]) +
                          (redA[2][lane] + redA[3][lane]));
    }
  } else {
    if (wave < 4) {
      const float yA = redA[wave][lane] + redA[wave + 4][lane];
      const float yB = redB[wave][lane] + redB[wave + 4][lane];
      outp[jA * 8192 + n] = tanh_hw(yA);
      outp[jB * 8192 + n] = tanh_hw(yB);
    }
  }
}

extern "C" void kernel_launch(void* const* d_in, const int* in_sizes, int n_in,
                              void* d_out, int out_size, void* d_ws, size_t ws_size,
                              hipStream_t stream) {
  const float* x    = (const float*)d_in[0];
  const float* t    = (const float*)d_in[1];
  const float* W1_0 = (const float*)d_in[2];
  const float* B1_0 = (const float*)d_in[3];
  const float* W2_0 = (const float*)d_in[4];
  const float* B2_0 = (const float*)d_in[5];
  const float* W1_1 = (const float*)d_in[6];
  const float* B1_1 = (const float*)d_in[7];
  const float* W2_1 = (const float*)d_in[8];
  const float* B2_1 = (const float*)d_in[9];
  const float* W1_2 = (const float*)d_in[10];
  const float* B1_2 = (const float*)d_in[11];
  const float* W2_2 = (const float*)d_in[12];
  const float* B2_2 = (const float*)d_in[13];
  const float* Wout = (const float*)d_in[14];
  const float* bout = (const float*)d_in[15];
  float* out = (float*)d_out;

  float* hA = (float*)d_ws;                  // 2 MB
  float* hB = hA + 64 * 8192;                // 2 MB
  float* G1 = hB + 64 * 8192;                // 64*64*16 floats (256 KB)
  float* G2 = G1 + 64 * 64 * P_CHEB;         // 256 KB

  kan_prep<<<dim3(256), 256, 0, stream>>>(
      W1_1, B1_1, W2_1, B2_1, W1_2, B1_2, W2_2, B2_2, G1, G2);
  kan_layer0<<<dim3(128, 16), 256, 0, stream>>>(
      x, t, W1_0, B1_0, W2_0, B2_0, bout, hA, out);
  kan_cheb<0><<<dim3(128, 8), 512, 0, stream>>>(hA, G1, Wout, hB);
  kan_cheb<1><<<dim3(128, 8), 512, 0, stream>>>(hB, G2, Wout, out);
}

// Round 16
// 134.217 us; speedup vs baseline: 1.9330x; 1.0506x over previous
//
#include <hip/hip_runtime.h>
#include <math.h>

// KAN-PINN forward, MI355X — round 16 (= round 15 resubmitted; broker timeout).
// r14 post-mortem: cheb layers are LDS-PIPE-bound: broadcast ds_read_b128 costs
// ~10cyc pipe occupancy regardless of broadcast (model: 2.1M reads -> 34us/layer,
// measured 33). Fix: 4 points per lane -> each G read feeds 4x FMA work.
// Block: 512thr/8 waves = 4 jpairs x 2 ihalves, 256 points, LDS 112KB, 1 blk/CU,
// grid (32,8)=256 blocks. VALU ~11.5us/layer, LDS ~11us, overlapped.

#define C2L 2.88539008177792681472f  // 2*log2(e)
#define P_CHEB 16
#define M_SAMP 32

__device__ __forceinline__ float tanh_hw(float z) {
  float e = __builtin_amdgcn_exp2f(z * C2L);
  float r = __builtin_amdgcn_rcpf(1.0f + e);
  return fmaf(r, -2.0f, 1.0f);
}

// ---------------- PREP: G[j][i][p] for both big layers ----------------
__global__ __launch_bounds__(256) void kan_prep(
    const float* __restrict__ W1_1, const float* __restrict__ B1_1,
    const float* __restrict__ W2_1, const float* __restrict__ B2_1,
    const float* __restrict__ W1_2, const float* __restrict__ B1_2,
    const float* __restrict__ W2_2, const float* __restrict__ B2_2,
    float* __restrict__ G1, float* __restrict__ G2)
{
  const int g = blockIdx.x * 256 + threadIdx.x;
  const int k = g & 7;
  const int ji = (g >> 3) & 4095;
  const int layer = g >> 15;                  // 0 or 1
  const float* __restrict__ W1 = layer ? W1_2 : W1_1;
  const float* __restrict__ B1 = layer ? B1_2 : B1_1;
  const float* __restrict__ W2 = layer ? W2_2 : W2_1;
  const float* __restrict__ B2 = layer ? B2_2 : B2_1;
  float* __restrict__ G = layer ? G2 : G1;

  const float w  = W1[ji * 8 + k];
  const float b  = B1[ji * 8 + k];
  const float w2 = W2[ji * 8 + k];

  float acc[P_CHEB];
#pragma unroll
  for (int p = 0; p < P_CHEB; ++p) acc[p] = 0.f;

  for (int m = 0; m < M_SAMP; ++m) {
    const float theta = ((float)m + 0.5f) * (3.14159265358979323846f / M_SAMP);
    const float c = cosf(theta);
    const float s = w2 * tanh_hw(fmaf(w, c, b));
    acc[0] += s;
    acc[1] = fmaf(s, c, acc[1]);
    const float c2 = c + c;
    float tp0 = 1.f, tp1 = c;
#pragma unroll
    for (int p = 2; p < P_CHEB; ++p) {
      const float t = fmaf(c2, tp1, -tp0);
      acc[p] = fmaf(s, t, acc[p]);
      tp0 = tp1; tp1 = t;
    }
  }
#pragma unroll
  for (int p = 0; p < P_CHEB; ++p) {
    float v = acc[p] * ((p == 0) ? (1.f / M_SAMP) : (2.f / M_SAMP));
    v += __shfl_xor(v, 1);
    v += __shfl_xor(v, 2);
    v += __shfl_xor(v, 4);                    // sum over k
    acc[p] = v;
  }
  if (k == 0) {
    float* __restrict__ dst = G + ji * P_CHEB;
    acc[0] += B2[ji];                         // fold B2 into T_0
#pragma unroll
    for (int p = 0; p < P_CHEB; ++p) dst[p] = acc[p];
  }
}

// ---------------- K0: layer0 (exact path, d_in=2) + out init ----------------
__global__ __launch_bounds__(256) void kan_layer0(
    const float* __restrict__ x, const float* __restrict__ t,
    const float* __restrict__ W1, const float* __restrict__ B1,   // (64,2,8)
    const float* __restrict__ W2, const float* __restrict__ B2,   // (64,2,8),(64,2)
    const float* __restrict__ bout,
    float* __restrict__ hA,      // [64][8192] = h0
    float* __restrict__ out)     // (8192,) <- b_out
{
  const int tid  = threadIdx.x;
  const int lane = tid & 63;
  const int wave = __builtin_amdgcn_readfirstlane(tid >> 6);
  const int bx = blockIdx.x, by = blockIdx.y;
  const int flat = by * 128 + bx;
  if (flat < 32) out[flat * 256 + tid] = bout[0];

  const int n = bx * 64 + lane;
  const int j = by * 4 + wave;
  const float hx = x[n], ht = t[n];
  float a0 = B2[j * 2 + 0];
  float a1 = B2[j * 2 + 1];
#pragma unroll
  for (int k = 0; k < 8; ++k) {
    float z0 = fmaf(hx, W1[j * 16 + k], B1[j * 16 + k]);
    a0 = fmaf(W2[j * 16 + k], tanh_hw(z0), a0);
    float z1 = fmaf(ht, W1[j * 16 + 8 + k], B1[j * 16 + 8 + k]);
    a1 = fmaf(W2[j * 16 + 8 + k], tanh_hw(z1), a1);
  }
  hA[j * 8192 + n] = tanh_hw(a0 + a1);
}

// ---------------- cheb layer, 4 points/lane ----------------
// grid (32, 8), block 512 (8 waves). Block: 256 points (n0..n0+255), 8 j.
// wave w: jpair = (w&3)*2 (local), ihalf = w>>2 (32 i each).
template <int HEAD>
__global__ __launch_bounds__(512, 2) void kan_cheb4(
    const float* __restrict__ hin,   // [64][8192], |h|<=1
    const float* __restrict__ G,     // [64][64][P_CHEB]
    const float* __restrict__ Wout,  // (1,64) if HEAD
    float* __restrict__ outp)        // hout [64][8192] or out (8192,)
{
  __shared__ float hsb[4 * 64 * 64];   // 64 KB: [q][i][lane], q = point plane
  __shared__ float Gsb[8 * 64 * 16];   // 32 KB: [jloc][i][p]
  __shared__ float redA[8][64][4];     // 8 KB
  __shared__ float redB[8][64][4];     // 8 KB
  const int tid  = threadIdx.x;
  const int lane = tid & 63;
  const int wave = __builtin_amdgcn_readfirstlane(tid >> 6);
  const int n0   = blockIdx.x * 256;

  // stage h: 256 rows (q*64+i) of 64 floats; wave handles rows w, w+8, ...
  for (int rr = 0; rr < 32; ++rr) {
    const int row = rr * 8 + wave;
    const int q = row >> 6, i = row & 63;
    hsb[row * 64 + lane] = hin[i * 8192 + n0 + q * 64 + lane];
  }
  // stage G slab (8 j): 8192 floats = 2048 float4, 512 thr x 4 coalesced
  {
    const float4* __restrict__ gsrc = (const float4*)(G + blockIdx.y * 8 * 64 * P_CHEB);
    float4* __restrict__ gdst = (float4*)Gsb;
#pragma unroll
    for (int qq = 0; qq < 4; ++qq) gdst[qq * 512 + tid] = gsrc[qq * 512 + tid];
  }
  __syncthreads();

  const int jloc = (wave & 3) * 2;
  const int jA = blockIdx.y * 8 + jloc;
  const int jB = jA + 1;
  const int ihalf = wave >> 2;
  const float4* __restrict__ gA = (const float4*)(Gsb + jloc * 64 * 16);
  const float4* __restrict__ gB = (const float4*)(Gsb + (jloc + 1) * 64 * 16);

  float accA[4] = {0.f, 0.f, 0.f, 0.f};
  float accB[4] = {0.f, 0.f, 0.f, 0.f};

  const int i0 = ihalf * 32;
  for (int i = i0; i < i0 + 32; ++i) {
    const float4 va0 = gA[i * 4 + 0];
    const float4 va1 = gA[i * 4 + 1];
    const float4 va2 = gA[i * 4 + 2];
    const float4 va3 = gA[i * 4 + 3];
    const float4 vb0 = gB[i * 4 + 0];
    const float4 vb1 = gB[i * 4 + 1];
    const float4 vb2 = gB[i * 4 + 2];
    const float4 vb3 = gB[i * 4 + 3];
#pragma unroll
    for (int q = 0; q < 4; ++q) {
      const float h  = hsb[(q * 64 + i) * 64 + lane];
      const float h2 = h + h;
      // shallow Chebyshev tree T_2..T_15 (depth 4)
      const float t2  = fmaf(h2, h,  -1.f);
      const float d2  = t2 + t2;
      const float t3  = fmaf(h2, t2, -h);
      const float t4  = fmaf(d2, t2, -1.f);
      const float d3  = t3 + t3;
      const float d4  = t4 + t4;
      const float t5  = fmaf(d3, t2, -h);
      const float t6  = fmaf(d3, t3, -1.f);
      const float t7  = fmaf(d4, t3, -h);
      const float t8  = fmaf(d4, t4, -1.f);
      const float d5  = t5 + t5;
      const float d6  = t6 + t6;
      const float d7  = t7 + t7;
      const float d8  = t8 + t8;
      const float t9  = fmaf(d5, t4, -h);
      const float t10 = fmaf(d5, t5, -1.f);
      const float t11 = fmaf(d6, t5, -h);
      const float t12 = fmaf(d6, t6, -1.f);
      const float t13 = fmaf(d7, t6, -h);
      const float t14 = fmaf(d7, t7, -1.f);
      const float t15 = fmaf(d8, t7, -h);

      float sA = va0.x;
      sA = fmaf(va0.y, h,   sA);
      sA = fmaf(va0.z, t2,  sA);
      sA = fmaf(va0.w, t3,  sA);
      sA = fmaf(va1.x, t4,  sA);
      sA = fmaf(va1.y, t5,  sA);
      sA = fmaf(va1.z, t6,  sA);
      sA = fmaf(va1.w, t7,  sA);
      sA = fmaf(va2.x, t8,  sA);
      sA = fmaf(va2.y, t9,  sA);
      sA = fmaf(va2.z, t10, sA);
      sA = fmaf(va2.w, t11, sA);
      sA = fmaf(va3.x, t12, sA);
      sA = fmaf(va3.y, t13, sA);
      sA = fmaf(va3.z, t14, sA);
      sA = fmaf(va3.w, t15, sA);
      accA[q] += sA;

      float sB = vb0.x;
      sB = fmaf(vb0.y, h,   sB);
      sB = fmaf(vb0.z, t2,  sB);
      sB = fmaf(vb0.w, t3,  sB);
      sB = fmaf(vb1.x, t4,  sB);
      sB = fmaf(vb1.y, t5,  sB);
      sB = fmaf(vb1.z, t6,  sB);
      sB = fmaf(vb1.w, t7,  sB);
      sB = fmaf(vb2.x, t8,  sB);
      sB = fmaf(vb2.y, t9,  sB);
      sB = fmaf(vb2.z, t10, sB);
      sB = fmaf(vb2.w, t11, sB);
      sB = fmaf(vb3.x, t12, sB);
      sB = fmaf(vb3.y, t13, sB);
      sB = fmaf(vb3.z, t14, sB);
      sB = fmaf(vb3.w, t15, sB);
      accB[q] += sB;
    }
  }

#pragma unroll
  for (int q = 0; q < 4; ++q) {
    redA[wave][lane][q] = accA[q];
    redB[wave][lane][q] = accB[q];
  }
  __syncthreads();

  if (HEAD) {
    if (wave < 4) {
      const float wA = Wout[jA], wB = Wout[jB];
#pragma unroll
      for (int q = 0; q < 4; ++q) {
        const float yA = redA[wave][lane][q] + redA[wave + 4][lane][q];
        const float yB = redB[wave][lane][q] + redB[wave + 4][lane][q];
        redA[wave][lane][q] = tanh_hw(yA) * wA + tanh_hw(yB) * wB;
      }
    }
    __syncthreads();
    if (wave == 0) {
#pragma unroll
      for (int q = 0; q < 4; ++q) {
        const float s = (redA[0][lane][q] + redA[1][lane][q]) +
                        (redA[2][lane][q] + redA[3][lane][q]);
        atomicAdd(&outp[n0 + q * 64 + lane], s);
      }
    }
  } else {
    if (wave < 4) {
#pragma unroll
      for (int q = 0; q < 4; ++q) {
        const float yA = redA[wave][lane][q] + redA[wave + 4][lane][q];
        const float yB = redB[wave][lane][q] + redB[wave + 4][lane][q];
        outp[jA * 8192 + n0 + q * 64 + lane] = tanh_hw(yA);
        outp[jB * 8192 + n0 + q * 64 + lane] = tanh_hw(yB);
      }
    }
  }
}

extern "C" void kernel_launch(void* const* d_in, const int* in_sizes, int n_in,
                              void* d_out, int out_size, void* d_ws, size_t ws_size,
                              hipStream_t stream) {
  const float* x    = (const float*)d_in[0];
  const float* t    = (const float*)d_in[1];
  const float* W1_0 = (const float*)d_in[2];
  const float* B1_0 = (const float*)d_in[3];
  const float* W2_0 = (const float*)d_in[4];
  const float* B2_0 = (const float*)d_in[5];
  const float* W1_1 = (const float*)d_in[6];
  const float* B1_1 = (const float*)d_in[7];
  const float* W2_1 = (const float*)d_in[8];
  const float* B2_1 = (const float*)d_in[9];
  const float* W1_2 = (const float*)d_in[10];
  const float* B1_2 = (const float*)d_in[11];
  const float* W2_2 = (const float*)d_in[12];
  const float* B2_2 = (const float*)d_in[13];
  const float* Wout = (const float*)d_in[14];
  const float* bout = (const float*)d_in[15];
  float* out = (float*)d_out;

  float* hA = (float*)d_ws;                  // 2 MB
  float* hB = hA + 64 * 8192;                // 2 MB
  float* G1 = hB + 64 * 8192;                // 64*64*16 floats (256 KB)
  float* G2 = G1 + 64 * 64 * P_CHEB;         // 256 KB

  kan_prep<<<dim3(256), 256, 0, stream>>>(
      W1_1, B1_1, W2_1, B2_1, W1_2, B1_2, W2_2, B2_2, G1, G2);
  kan_layer0<<<dim3(128, 16), 256, 0, stream>>>(
      x, t, W1_0, B1_0, W2_0, B2_0, bout, hA, out);
  kan_cheb4<0><<<dim3(32, 8), 512, 0, stream>>>(hA, G1, Wout, hB);
  kan_cheb4<1><<<dim3(32, 8), 512, 0, stream>>>(hB, G2, Wout, out);
}